// Round 3
// baseline (246.828 us; speedup 1.0000x reference)
//
#include <hip/hip_runtime.h>

#define N_PTS 8192
#define D_DIM 256
#define BN 256              // set1 rows per block (n)
#define BM 128              // set2 rows per block (m)
#define BK 64
#define INF_BITS 0x7F800000u

typedef __attribute__((ext_vector_type(8))) short short8;
typedef __attribute__((ext_vector_type(16))) float f32x16;

__device__ unsigned g_cnt;   // last-block-done counter (reset by prep each launch)

// async global->LDS, 16B/lane; LDS dest = wave-uniform base + lane*16
__device__ __forceinline__ void gload_lds16(const ushort* g, ushort* l) {
    __builtin_amdgcn_global_load_lds(
        (const __attribute__((address_space(1))) void*)g,
        (__attribute__((address_space(3))) void*)l, 16, 0, 0);
}

__device__ __forceinline__ ushort f2bf(float x) {
    unsigned u = __float_as_uint(x);
    return (ushort)((u + 0x7FFFu + ((u >> 16) & 1u)) >> 16);  // RNE, no NaNs here
}

// ---- fused prep: bf16 convert + row sqnorms (fp32 exact) + INF init ----
__global__ void prep_kernel(const float* __restrict__ s1, const float* __restrict__ s2,
                            ushort* __restrict__ b1, ushort* __restrict__ b2,
                            float* __restrict__ sq1, float* __restrict__ sq2,
                            unsigned* __restrict__ rowmin2, unsigned* __restrict__ colmin2) {
    const int half = N_PTS * D_DIM;
    int t = blockIdx.x * 256 + threadIdx.x;
    if (t == 0) atomicExch(&g_cnt, 0u);          // reset the done-counter every launch
    int e = t * 8;
    bool first = e < half;
    const float* src = first ? s1 : s2;
    ushort* dst = first ? b1 : b2;
    int off = first ? e : e - half;
    float4 v0 = *(const float4*)(src + off);
    float4 v1 = *(const float4*)(src + off + 4);
    float s = v0.x * v0.x + v0.y * v0.y + v0.z * v0.z + v0.w * v0.w
            + v1.x * v1.x + v1.y * v1.y + v1.z * v1.z + v1.w * v1.w;
    ushort4 o0 = { f2bf(v0.x), f2bf(v0.y), f2bf(v0.z), f2bf(v0.w) };
    ushort4 o1 = { f2bf(v1.x), f2bf(v1.y), f2bf(v1.z), f2bf(v1.w) };
    *(ushort4*)(dst + off)     = o0;
    *(ushort4*)(dst + off + 4) = o1;
    // one row = 32 consecutive threads; xor masks <=16 stay inside the half-wave
    #pragma unroll
    for (int m = 1; m <= 16; m <<= 1) s += __shfl_xor(s, m, 64);
    int sub = threadIdx.x & 31;
    int row = off >> 8;
    if (sub == 0) (first ? sq1 : sq2)[row] = s;
    if (sub == 1) (first ? rowmin2 : colmin2)[row] = INF_BITS;
}

// ---- MFMA gram (32x32x16) + fused d^2 + row/col min + fused final reduce ----
// LDS is FRAGMENT-MAJOR: each 32x32x16 MFMA fragment is a contiguous 1KB block
// in lane order (slot = frag*64 + lane, 16B/slot). Staging writes it directly
// (gload_lds dest is linear base+lane*16; the per-lane GLOBAL address encodes
// the fragment layout: row = l&31, k = (l>>5)*8). ds_reads become base +
// compile-time offset, stride-1, conflict-free by construction, zero VALU.
// Operands SWAPPED vs the gram convention: A-operand = set2 (m), B-operand =
// set1 (n), so C/D col = lane&31 = n and row = reg-pattern = m. The set1
// nearest-min (over all local m) is then fully IN-LANE (no shuffles).
__global__ __launch_bounds__(256, 2) void tile_kernel(
    const ushort* __restrict__ B1, const ushort* __restrict__ B2,
    const float* __restrict__ sq1, const float* __restrict__ sq2,
    unsigned* __restrict__ rowmin2, unsigned* __restrict__ colmin2,
    float* __restrict__ out) {
    __shared__ ushort As[BN * BK] __attribute__((aligned(16)));   // set1, 32 KB
    __shared__ ushort Bs[BM * BK] __attribute__((aligned(16)));   // set2, 16 KB
    __shared__ unsigned rs[BN];
    __shared__ unsigned cs[BM];
    __shared__ float wsum[4];
    __shared__ unsigned lastf;

    const int tid  = threadIdx.x;
    const int lane = tid & 63;
    const int w    = tid >> 6;          // 4 waves: 2 (n) x 2 (m)
    const int hi   = lane >> 5;
    const int l31  = lane & 31;
    const int n_off = (w >> 1) * 128;   // wave tile: 128(n) x 64(m)
    const int m_off = (w & 1) * 64;
    const int n0 = blockIdx.y * BN;
    const int m0 = blockIdx.x * BM;

    rs[tid] = INF_BITS;
    if (tid < BM) cs[tid] = INF_BITS;

    f32x16 acc[2][4];                   // [m-frag][n-frag], 128 AGPR
    #pragma unroll
    for (int fm = 0; fm < 2; fm++)
        #pragma unroll
        for (int fn = 0; fn < 4; fn++)
            acc[fm][fn] = (f32x16){0.f,0.f,0.f,0.f,0.f,0.f,0.f,0.f,
                                   0.f,0.f,0.f,0.f,0.f,0.f,0.f,0.f};

    // stage source bases: thread writes fragment element (row = l31, k = w*16+hi*8)
    const ushort* gA = B1 + (size_t)(n0 + l31) * D_DIM + w * 16 + hi * 8;
    const ushort* gB = B2 + (size_t)(m0 + l31) * D_DIM + w * 16 + hi * 8;

    #pragma unroll
    for (int t = 0; t < D_DIM / BK; ++t) {      // 4 K-tiles
        // As: 8 rounds of 256 slots; round r stages rows r*32..+31 (frag fn=r, ks=w)
        #pragma unroll
        for (int r = 0; r < 8; r++)
            gload_lds16(gA + t * BK + r * 32 * D_DIM, &As[(r * 256 + w * 64) * 8]);
        // Bs: 4 rounds
        #pragma unroll
        for (int r = 0; r < 4; r++)
            gload_lds16(gB + t * BK + r * 32 * D_DIM, &Bs[(r * 256 + w * 64) * 8]);
        __syncthreads();                         // stage drained (vmcnt 0)

        #pragma unroll
        for (int ks = 0; ks < 4; ks++) {
            short8 av[2], bv[4];
            #pragma unroll
            for (int fm = 0; fm < 2; fm++)
                av[fm] = *(const short8*)&Bs[(((w & 1) * 2 + fm) * 4 + ks) * 512 + lane * 8];
            #pragma unroll
            for (int fn = 0; fn < 4; fn++)
                bv[fn] = *(const short8*)&As[(((w >> 1) * 4 + fn) * 4 + ks) * 512 + lane * 8];
            #pragma unroll
            for (int fm = 0; fm < 2; fm++)
                #pragma unroll
                for (int fn = 0; fn < 4; fn++)
                    acc[fm][fn] = __builtin_amdgcn_mfma_f32_32x32x16_bf16(
                        av[fm], bv[fn], acc[fm][fn], 0, 0, 0);
        }
        __syncthreads();
    }

    // epilogue. C/D: col = lane&31 = n, row = (r&3)+8*(r>>2)+4*hi = m (in-frag)
    float sq1v[4];
    #pragma unroll
    for (int fn = 0; fn < 4; fn++) sq1v[fn] = sq1[n0 + n_off + fn * 32 + l31];
    float rmin[4];
    #pragma unroll
    for (int fn = 0; fn < 4; fn++) rmin[fn] = __uint_as_float(INF_BITS);
    float cmn[32];

    #pragma unroll
    for (int fm = 0; fm < 2; fm++) {
        #pragma unroll
        for (int q = 0; q < 4; q++) {
            float4 s2 = *(const float4*)&sq2[m0 + m_off + fm * 32 + hi * 4 + q * 8];
            float s2a[4] = { s2.x, s2.y, s2.z, s2.w };
            #pragma unroll
            for (int rr = 0; rr < 4; rr++) {
                const int r = q * 4 + rr;
                float cm = __uint_as_float(INF_BITS);
                #pragma unroll
                for (int fn = 0; fn < 4; fn++) {
                    float d2 = fmaxf(fmaf(-2.f, acc[fm][fn][r], sq1v[fn] + s2a[rr]), 0.f);
                    rmin[fn] = fminf(rmin[fn], d2);
                    cm = fminf(cm, d2);
                }
                cmn[fm * 16 + r] = cm;
            }
        }
    }
    // set1 mins: fully reduced over this wave's 64 m already -> LDS atomic (2-way)
    #pragma unroll
    for (int fn = 0; fn < 4; fn++)
        atomicMin(&rs[n_off + fn * 32 + l31], __float_as_uint(rmin[fn]));
    // set2 mins: reduce over the 32 n-cols (lane&31); masks <=16 stay in hi-half
    #pragma unroll
    for (int m = 1; m <= 16; m <<= 1)
        #pragma unroll
        for (int i = 0; i < 32; i++)
            cmn[i] = fminf(cmn[i], __shfl_xor(cmn[i], m, 64));
    if (l31 == 0) {
        #pragma unroll
        for (int fm = 0; fm < 2; fm++)
            #pragma unroll
            for (int r = 0; r < 16; r++)
                atomicMin(&cs[m_off + fm * 32 + (r & 3) + (r >> 2) * 8 + hi * 4],
                          __float_as_uint(cmn[fm * 16 + r]));
    }
    __syncthreads();

    atomicMin(&rowmin2[n0 + tid], rs[tid]);          // BN == 256 == blockDim
    if (tid < BM) atomicMin(&colmin2[m0 + tid], cs[tid]);

    // ---- fused final reduce: last block computes mean(sqrt(min d^2)) ----
    __threadfence();
    if (tid == 0)
        lastf = (atomicAdd(&g_cnt, 1u) == (unsigned)(gridDim.x * gridDim.y - 1));
    __syncthreads();
    if (lastf) {
        float s = 0.f;
        #pragma unroll 8
        for (int j = 0; j < 64; ++j) {           // rowmin2||colmin2 contiguous 16384
            unsigned u = __hip_atomic_load(&rowmin2[tid + 256 * j],
                                           __ATOMIC_RELAXED, __HIP_MEMORY_SCOPE_AGENT);
            s += sqrtf(__uint_as_float(u));
        }
        #pragma unroll
        for (int m = 1; m <= 32; m <<= 1) s += __shfl_xor(s, m, 64);
        if (lane == 0) wsum[w] = s;
        __syncthreads();
        if (tid == 0) out[0] = (wsum[0] + wsum[1] + wsum[2] + wsum[3]) / (float)N_PTS;
    }
}

extern "C" void kernel_launch(void* const* d_in, const int* in_sizes, int n_in,
                              void* d_out, int out_size, void* d_ws, size_t ws_size,
                              hipStream_t stream) {
    const float* set1 = (const float*)d_in[0];
    const float* set2 = (const float*)d_in[1];
    float* out = (float*)d_out;

    // workspace: rowmin2[8192] | colmin2[8192] (contiguous!) | sq1 | sq2 | b1 | b2
    unsigned* rowmin2 = (unsigned*)d_ws;
    unsigned* colmin2 = rowmin2 + N_PTS;
    float* sq1 = (float*)(colmin2 + N_PTS);
    float* sq2 = sq1 + N_PTS;
    ushort* b1 = (ushort*)((char*)d_ws + 128 * 1024);       // 256B-aligned, past headers
    ushort* b2 = b1 + (size_t)N_PTS * D_DIM;

    prep_kernel<<<(2 * N_PTS * D_DIM) / (256 * 8), 256, 0, stream>>>(
        set1, set2, b1, b2, sq1, sq2, rowmin2, colmin2);
    tile_kernel<<<dim3(N_PTS / BM, N_PTS / BN), 256, 0, stream>>>(
        b1, b2, sq1, sq2, rowmin2, colmin2, out);
}

// Round 4
// 240.387 us; speedup vs baseline: 1.0268x; 1.0268x over previous
//
#include <hip/hip_runtime.h>

#define N_PTS 8192
#define D_DIM 256
#define BN 256              // set1 rows per block (n)
#define BM 128              // set2 rows per block (m)
#define INF_BITS 0x7F800000u

typedef __attribute__((ext_vector_type(8))) short short8;
typedef __attribute__((ext_vector_type(16))) float f32x16;

__device__ unsigned g_cnt;   // last-block-done counter (reset by prep each launch)

__device__ __forceinline__ ushort f2bf(float x) {
    unsigned u = __float_as_uint(x);
    return (ushort)((u + 0x7FFFu + ((u >> 16) & 1u)) >> 16);  // RNE, no NaNs here
}

// ---- prep: pack to FRAGMENT-MAJOR + row sqnorms + INF init ----
// One wave per 32-row panel. Packed layout (verified by R3's passing run):
// panel p (rows p*32..+31), slice s (k = s*16..+15), lane l = (row&31) + 32*hi
// holds 8 bf16 at k = s*16 + hi*8. Offset (shorts) = p*8192 + s*512 + lane*8.
// Reads: lane pairs (l, l+32) cover one contiguous 64B row segment (full
// sectors). Writes: 64 lanes x 16B contiguous = perfectly coalesced 1KB.
__global__ __launch_bounds__(64) void prep_kernel(
        const float* __restrict__ s1, const float* __restrict__ s2,
        ushort* __restrict__ p1, ushort* __restrict__ p2,
        float* __restrict__ sq1, float* __restrict__ sq2,
        unsigned* __restrict__ rowmin2, unsigned* __restrict__ colmin2) {
    const int wid = blockIdx.x;                 // 512 blocks = 512 panels
    if (wid == 0 && threadIdx.x == 0) atomicExch(&g_cnt, 0u);
    const bool first = wid < 256;
    const int p = first ? wid : wid - 256;
    const float* src = first ? s1 : s2;
    ushort* outp = (first ? p1 : p2) + (size_t)p * 8192 + threadIdx.x * 8;
    const int lane = threadIdx.x, hi = lane >> 5, l31 = lane & 31;
    const float* rowp = src + (size_t)(p * 32 + l31) * D_DIM + hi * 8;
    float s = 0.f;
    #pragma unroll
    for (int sl = 0; sl < 16; ++sl) {
        float4 v0 = *(const float4*)(rowp + sl * 16);
        float4 v1 = *(const float4*)(rowp + sl * 16 + 4);
        s += v0.x * v0.x + v0.y * v0.y + v0.z * v0.z + v0.w * v0.w
           + v1.x * v1.x + v1.y * v1.y + v1.z * v1.z + v1.w * v1.w;
        ushort4 o0 = { f2bf(v0.x), f2bf(v0.y), f2bf(v0.z), f2bf(v0.w) };
        ushort4 o1 = { f2bf(v1.x), f2bf(v1.y), f2bf(v1.z), f2bf(v1.w) };
        *(ushort4*)(outp + sl * 512)     = o0;
        *(ushort4*)(outp + sl * 512 + 4) = o1;
    }
    s += __shfl_xor(s, 32, 64);                 // pair (l, l+32) -> full row sum
    if (hi == 0) {
        (first ? sq1 : sq2)[p * 32 + l31] = s;
        (first ? rowmin2 : colmin2)[p * 32 + l31] = INF_BITS;
    }
}

// ---- tile: direct-to-register MFMA gram, NO operand LDS, NO main-loop barriers ----
// Wave tile 128(n) x 64(m); 32x32x16 MFMA, operands SWAPPED (A=set2, B=set1) so
// the set1 nearest-min is fully in-lane (C/D col = lane&31 = n). 16 K-slices,
// 6 coalesced 1KB fragment loads + 8 MFMA each, 2-slice-ahead register pipeline
// (all indices compile-time under full unroll). Epilogue + fused final reduce
// verified by R3.
__global__ __launch_bounds__(256, 2) void tile_kernel(
    const ushort* __restrict__ P1, const ushort* __restrict__ P2,
    const float* __restrict__ sq1, const float* __restrict__ sq2,
    unsigned* __restrict__ rowmin2, unsigned* __restrict__ colmin2,
    float* __restrict__ out) {
    __shared__ unsigned rs[BN];
    __shared__ unsigned cs[BM];
    __shared__ float wsum[4];
    __shared__ unsigned lastf;

    const int tid  = threadIdx.x;
    const int lane = tid & 63;
    const int w    = tid >> 6;          // 4 waves: 2 (n) x 2 (m)
    const int hi   = lane >> 5;
    const int l31  = lane & 31;
    const int n_off = (w >> 1) * 128;   // wave tile: 128(n) x 64(m)
    const int m_off = (w & 1) * 64;

    // bijective XCD swizzle (2048 % 8 == 0): contiguous grid chunk per XCD
    unsigned bid = blockIdx.y * gridDim.x + blockIdx.x;
    unsigned swz = (bid & 7) * ((N_PTS / BM) * (N_PTS / BN) / 8) + (bid >> 3);
    const int m0 = (int)(swz & (N_PTS / BM - 1)) * BM;   // gridDim.x = 64
    const int n0 = (int)(swz >> 6) * BN;

    rs[tid] = INF_BITS;
    if (tid < BM) cs[tid] = INF_BITS;
    __syncthreads();

    f32x16 acc[2][4];                   // [m-frag][n-frag], 128 regs
    #pragma unroll
    for (int fm = 0; fm < 2; fm++)
        #pragma unroll
        for (int fn = 0; fn < 4; fn++)
            acc[fm][fn] = (f32x16){0.f,0.f,0.f,0.f,0.f,0.f,0.f,0.f,
                                   0.f,0.f,0.f,0.f,0.f,0.f,0.f,0.f};

    // fragment base pointers (shorts); panel stride 8192, slice stride 512
    const ushort* pA = P2 + (size_t)((m0 + m_off) >> 5) * 8192 + lane * 8;
    const ushort* pB = P1 + (size_t)((n0 + n_off) >> 5) * 8192 + lane * 8;

    short8 a[3][2], b[3][4];            // 3-deep rotation, 2 slices ahead
    #pragma unroll
    for (int s = 0; s < 2; ++s) {
        #pragma unroll
        for (int fm = 0; fm < 2; fm++)
            a[s][fm] = *(const short8*)(pA + (size_t)fm * 8192 + s * 512);
        #pragma unroll
        for (int fn = 0; fn < 4; fn++)
            b[s][fn] = *(const short8*)(pB + (size_t)fn * 8192 + s * 512);
    }
    #pragma unroll
    for (int s = 0; s < 16; ++s) {
        const int cur = s % 3;
        if (s + 2 < 16) {
            const int nxt = (s + 2) % 3;
            #pragma unroll
            for (int fm = 0; fm < 2; fm++)
                a[nxt][fm] = *(const short8*)(pA + (size_t)fm * 8192 + (s + 2) * 512);
            #pragma unroll
            for (int fn = 0; fn < 4; fn++)
                b[nxt][fn] = *(const short8*)(pB + (size_t)fn * 8192 + (s + 2) * 512);
        }
        #pragma unroll
        for (int fm = 0; fm < 2; fm++)
            #pragma unroll
            for (int fn = 0; fn < 4; fn++)
                acc[fm][fn] = __builtin_amdgcn_mfma_f32_32x32x16_bf16(
                    a[cur][fm], b[cur][fn], acc[fm][fn], 0, 0, 0);
    }

    // epilogue (R3-verified). C/D: col = lane&31 = n, row = (r&3)+8*(r>>2)+4*hi = m
    float sq1v[4];
    #pragma unroll
    for (int fn = 0; fn < 4; fn++) sq1v[fn] = sq1[n0 + n_off + fn * 32 + l31];
    float rmin[4];
    #pragma unroll
    for (int fn = 0; fn < 4; fn++) rmin[fn] = __uint_as_float(INF_BITS);
    float cmn[32];

    #pragma unroll
    for (int fm = 0; fm < 2; fm++) {
        #pragma unroll
        for (int q = 0; q < 4; q++) {
            float4 s2 = *(const float4*)&sq2[m0 + m_off + fm * 32 + hi * 4 + q * 8];
            float s2a[4] = { s2.x, s2.y, s2.z, s2.w };
            #pragma unroll
            for (int rr = 0; rr < 4; rr++) {
                const int r = q * 4 + rr;
                float cm = __uint_as_float(INF_BITS);
                #pragma unroll
                for (int fn = 0; fn < 4; fn++) {
                    float d2 = fmaxf(fmaf(-2.f, acc[fm][fn][r], sq1v[fn] + s2a[rr]), 0.f);
                    rmin[fn] = fminf(rmin[fn], d2);
                    cm = fminf(cm, d2);
                }
                cmn[fm * 16 + r] = cm;
            }
        }
    }
    // set1 mins: fully reduced over this wave's 64 m already -> LDS atomic
    #pragma unroll
    for (int fn = 0; fn < 4; fn++)
        atomicMin(&rs[n_off + fn * 32 + l31], __float_as_uint(rmin[fn]));
    // set2 mins: reduce over the 32 n-cols (lane&31); masks <=16 stay in hi-half
    #pragma unroll
    for (int m = 1; m <= 16; m <<= 1)
        #pragma unroll
        for (int i = 0; i < 32; i++)
            cmn[i] = fminf(cmn[i], __shfl_xor(cmn[i], m, 64));
    if (l31 == 0) {
        #pragma unroll
        for (int fm = 0; fm < 2; fm++)
            #pragma unroll
            for (int r = 0; r < 16; r++)
                atomicMin(&cs[m_off + fm * 32 + (r & 3) + (r >> 2) * 8 + hi * 4],
                          __float_as_uint(cmn[fm * 16 + r]));
    }
    __syncthreads();

    atomicMin(&rowmin2[n0 + tid], rs[tid]);          // BN == 256 == blockDim
    if (tid < BM) atomicMin(&colmin2[m0 + tid], cs[tid]);

    // ---- fused final reduce: last block computes mean(sqrt(min d^2)) ----
    __threadfence();
    if (tid == 0)
        lastf = (atomicAdd(&g_cnt, 1u) == (unsigned)(gridDim.x * gridDim.y - 1));
    __syncthreads();
    if (lastf) {
        float s = 0.f;
        #pragma unroll 8
        for (int j = 0; j < 64; ++j) {           // rowmin2||colmin2 contiguous 16384
            unsigned u = __hip_atomic_load(&rowmin2[tid + 256 * j],
                                           __ATOMIC_RELAXED, __HIP_MEMORY_SCOPE_AGENT);
            s += sqrtf(__uint_as_float(u));
        }
        #pragma unroll
        for (int m = 1; m <= 32; m <<= 1) s += __shfl_xor(s, m, 64);
        if (lane == 0) wsum[w] = s;
        __syncthreads();
        if (tid == 0) out[0] = (wsum[0] + wsum[1] + wsum[2] + wsum[3]) / (float)N_PTS;
    }
}

extern "C" void kernel_launch(void* const* d_in, const int* in_sizes, int n_in,
                              void* d_out, int out_size, void* d_ws, size_t ws_size,
                              hipStream_t stream) {
    const float* set1 = (const float*)d_in[0];
    const float* set2 = (const float*)d_in[1];
    float* out = (float*)d_out;

    // workspace: rowmin2[8192] | colmin2[8192] (contiguous!) | sq1 | sq2 | p1 | p2
    unsigned* rowmin2 = (unsigned*)d_ws;
    unsigned* colmin2 = rowmin2 + N_PTS;
    float* sq1 = (float*)(colmin2 + N_PTS);
    float* sq2 = sq1 + N_PTS;
    ushort* p1 = (ushort*)((char*)d_ws + 128 * 1024);       // 256B-aligned, past headers
    ushort* p2 = p1 + (size_t)N_PTS * D_DIM;

    prep_kernel<<<512, 64, 0, stream>>>(
        set1, set2, p1, p2, sq1, sq2, rowmin2, colmin2);
    tile_kernel<<<dim3(N_PTS / BM, N_PTS / BN), 256, 0, stream>>>(
        p1, p2, sq1, sq2, rowmin2, colmin2, out);
}

// Round 5
// 227.677 us; speedup vs baseline: 1.0841x; 1.0558x over previous
//
#include <hip/hip_runtime.h>

#define N_PTS 8192
#define D_DIM 256
#define BN 256              // set1 rows per block (n)
#define BM 128              // set2 rows per block (m)
#define INF_BITS 0x7F800000u

typedef __attribute__((ext_vector_type(8))) short short8;
typedef __attribute__((ext_vector_type(16))) float f32x16;

__device__ unsigned g_cnt;   // last-block-done counter (reset by prep each launch)

// async global->LDS, 16B/lane; LDS dest = wave-uniform base + lane*16
__device__ __forceinline__ void gload_lds16(const ushort* g, ushort* l) {
    __builtin_amdgcn_global_load_lds(
        (const __attribute__((address_space(1))) void*)g,
        (__attribute__((address_space(3))) void*)l, 16, 0, 0);
}

__device__ __forceinline__ ushort f2bf(float x) {
    unsigned u = __float_as_uint(x);
    return (ushort)((u + 0x7FFFu + ((u >> 16) & 1u)) >> 16);  // RNE, no NaNs here
}

// ---- prep: pack to FRAGMENT-MAJOR panels + row sqnorms + INF init ----
// Packed layout (R3/R4-verified): panel p (32 rows), slice s (k=s*16..+15),
// lane l holds 8 bf16 of row (l&31) at k = s*16 + (l>>5)*8.
// Offset (shorts) = p*8192 + s*512 + l*8. One block per panel, 4 waves split
// the 16 slices (4 each) -> 2048 waves total (8/CU, latency well hidden).
__global__ __launch_bounds__(256) void prep_kernel(
        const float* __restrict__ s1, const float* __restrict__ s2,
        ushort* __restrict__ p1, ushort* __restrict__ p2,
        float* __restrict__ sq1, float* __restrict__ sq2,
        unsigned* __restrict__ rowmin2, unsigned* __restrict__ colmin2) {
    const int pg = blockIdx.x;                  // 512 blocks = 512 panels
    if (pg == 0 && threadIdx.x == 0) atomicExch(&g_cnt, 0u);
    const bool first = pg < 256;
    const int p = first ? pg : pg - 256;
    const float* src = first ? s1 : s2;
    ushort* dst = first ? p1 : p2;
    const int tid = threadIdx.x, sg = tid >> 6, lane = tid & 63;
    const int hi = lane >> 5, l31 = lane & 31;
    const float* rowp = src + (size_t)(p * 32 + l31) * D_DIM + sg * 64 + hi * 8;
    ushort* outp = dst + (size_t)p * 8192 + lane * 8;
    float s = 0.f;
    #pragma unroll
    for (int sl = 0; sl < 4; ++sl) {            // wave sg covers slices sg*4..+3
        float4 v0 = *(const float4*)(rowp + sl * 16);
        float4 v1 = *(const float4*)(rowp + sl * 16 + 4);
        s += v0.x * v0.x + v0.y * v0.y + v0.z * v0.z + v0.w * v0.w
           + v1.x * v1.x + v1.y * v1.y + v1.z * v1.z + v1.w * v1.w;
        ushort4 o0 = { f2bf(v0.x), f2bf(v0.y), f2bf(v0.z), f2bf(v0.w) };
        ushort4 o1 = { f2bf(v1.x), f2bf(v1.y), f2bf(v1.z), f2bf(v1.w) };
        *(ushort4*)(outp + (sg * 4 + sl) * 512)     = o0;
        *(ushort4*)(outp + (sg * 4 + sl) * 512 + 4) = o1;
    }
    s += __shfl_xor(s, 32, 64);                 // combine the two k-halves
    __shared__ float part[4][32];
    if (hi == 0) part[sg][l31] = s;
    __syncthreads();
    if (tid < 32) {
        float tot = part[0][tid] + part[1][tid] + part[2][tid] + part[3][tid];
        (first ? sq1 : sq2)[p * 32 + tid] = tot;
        (first ? rowmin2 : colmin2)[p * 32 + tid] = INF_BITS;
    }
}

// ---- tile: R0's proven schedule + packed staging + 32x32x16 MFMA ----
// Per K-tile: 12 bulk gload_lds (each a fully-contiguous 1KB fragment from the
// packed global -> linear fragment-major LDS), one sync, then 4 k-slices of
// {6 stride-1 conflict-free ds_read_b128 + 8 MFMA}, one sync. Operands SWAPPED
// (A=set2, B=set1) so the set1 nearest-min is fully in-lane (C/D col=lane&31=n).
// Epilogue + fused final reduce verified in R3/R4.
__global__ __launch_bounds__(256, 2) void tile_kernel(
    const ushort* __restrict__ P1, const ushort* __restrict__ P2,
    const float* __restrict__ sq1, const float* __restrict__ sq2,
    unsigned* __restrict__ rowmin2, unsigned* __restrict__ colmin2,
    float* __restrict__ out) {
    __shared__ ushort As[8 * 4 * 512] __attribute__((aligned(16)));  // set1: 8 panels x 4 slices, 32 KB
    __shared__ ushort Bs[4 * 4 * 512] __attribute__((aligned(16)));  // set2: 4 panels x 4 slices, 16 KB
    __shared__ unsigned rs[BN];
    __shared__ unsigned cs[BM];
    __shared__ float wsum[4];
    __shared__ unsigned lastf;

    const int tid  = threadIdx.x;
    const int lane = tid & 63;
    const int w    = tid >> 6;          // 4 waves: 2 (n) x 2 (m)
    const int hi   = lane >> 5;
    const int l31  = lane & 31;
    const int n_off = (w >> 1) * 128;   // wave tile: 128(n) x 64(m)
    const int m_off = (w & 1) * 64;

    // bijective XCD swizzle (2048 % 8 == 0): contiguous grid chunk per XCD
    unsigned bid = blockIdx.y * gridDim.x + blockIdx.x;
    unsigned swz = (bid & 7) * 256 + (bid >> 3);
    const int m0 = (int)(swz & 63) * BM;                 // gridDim.x = 64
    const int n0 = (int)(swz >> 6) * BN;

    rs[tid] = INF_BITS;
    if (tid < BM) cs[tid] = INF_BITS;

    f32x16 acc[2][4];                   // [m-frag][n-frag], 128 acc regs
    #pragma unroll
    for (int fm = 0; fm < 2; fm++)
        #pragma unroll
        for (int fn = 0; fn < 4; fn++)
            acc[fm][fn] = (f32x16){0.f,0.f,0.f,0.f,0.f,0.f,0.f,0.f,
                                   0.f,0.f,0.f,0.f,0.f,0.f,0.f,0.f};

    // packed stage sources (shorts): panel stride 8192, slice stride 512
    const ushort* gA = P1 + (size_t)(n0 >> 5) * 8192 + lane * 8;
    const ushort* gB = P2 + (size_t)(m0 >> 5) * 8192 + lane * 8;

    #pragma unroll
    for (int t = 0; t < 4; ++t) {       // 4 K-tiles of 64
        // As: 8 panels x 4 slices = 32 wave-chunks, 8 rounds of 4 waves
        #pragma unroll
        for (int r = 0; r < 8; r++) {
            int g = r * 4 + w;          // chunk id: panel = g>>2, slice = g&3
            gload_lds16(gA + (size_t)(g >> 2) * 8192 + (t * 4 + (g & 3)) * 512,
                        &As[g * 512]);
        }
        // Bs: 4 panels x 4 slices = 16 wave-chunks, 4 rounds
        #pragma unroll
        for (int r = 0; r < 4; r++) {
            int g = r * 4 + w;
            gload_lds16(gB + (size_t)(g >> 2) * 8192 + (t * 4 + (g & 3)) * 512,
                        &Bs[g * 512]);
        }
        __syncthreads();                // stage drained (vmcnt 0 in barrier)

        #pragma unroll
        for (int ks = 0; ks < 4; ks++) {
            short8 av[2], bv[4];
            #pragma unroll
            for (int fm = 0; fm < 2; fm++)
                av[fm] = *(const short8*)&Bs[(((w & 1) * 2 + fm) * 4 + ks) * 512 + lane * 8];
            #pragma unroll
            for (int fn = 0; fn < 4; fn++)
                bv[fn] = *(const short8*)&As[(((w >> 1) * 4 + fn) * 4 + ks) * 512 + lane * 8];
            #pragma unroll
            for (int fm = 0; fm < 2; fm++)
                #pragma unroll
                for (int fn = 0; fn < 4; fn++)
                    acc[fm][fn] = __builtin_amdgcn_mfma_f32_32x32x16_bf16(
                        av[fm], bv[fn], acc[fm][fn], 0, 0, 0);
        }
        __syncthreads();
    }

    // epilogue (R3/R4-verified). C/D: col = lane&31 = n, row = (r&3)+8*(r>>2)+4*hi = m
    float sq1v[4];
    #pragma unroll
    for (int fn = 0; fn < 4; fn++) sq1v[fn] = sq1[n0 + n_off + fn * 32 + l31];
    float rmin[4];
    #pragma unroll
    for (int fn = 0; fn < 4; fn++) rmin[fn] = __uint_as_float(INF_BITS);
    float cmn[32];

    #pragma unroll
    for (int fm = 0; fm < 2; fm++) {
        #pragma unroll
        for (int q = 0; q < 4; q++) {
            float4 s2 = *(const float4*)&sq2[m0 + m_off + fm * 32 + hi * 4 + q * 8];
            float s2a[4] = { s2.x, s2.y, s2.z, s2.w };
            #pragma unroll
            for (int rr = 0; rr < 4; rr++) {
                const int r = q * 4 + rr;
                float cm = __uint_as_float(INF_BITS);
                #pragma unroll
                for (int fn = 0; fn < 4; fn++) {
                    float d2 = fmaxf(fmaf(-2.f, acc[fm][fn][r], sq1v[fn] + s2a[rr]), 0.f);
                    rmin[fn] = fminf(rmin[fn], d2);
                    cm = fminf(cm, d2);
                }
                cmn[fm * 16 + r] = cm;
            }
        }
    }
    // set1 mins: fully reduced over this wave's 64 m already -> LDS atomic
    #pragma unroll
    for (int fn = 0; fn < 4; fn++)
        atomicMin(&rs[n_off + fn * 32 + l31], __float_as_uint(rmin[fn]));
    // set2 mins: reduce over the 32 n-cols (lane&31); masks <=16 stay in hi-half
    #pragma unroll
    for (int m = 1; m <= 16; m <<= 1)
        #pragma unroll
        for (int i = 0; i < 32; i++)
            cmn[i] = fminf(cmn[i], __shfl_xor(cmn[i], m, 64));
    if (l31 == 0) {
        #pragma unroll
        for (int fm = 0; fm < 2; fm++)
            #pragma unroll
            for (int r = 0; r < 16; r++)
                atomicMin(&cs[m_off + fm * 32 + (r & 3) + (r >> 2) * 8 + hi * 4],
                          __float_as_uint(cmn[fm * 16 + r]));
    }
    __syncthreads();

    atomicMin(&rowmin2[n0 + tid], rs[tid]);          // BN == 256 == blockDim
    if (tid < BM) atomicMin(&colmin2[m0 + tid], cs[tid]);

    // ---- fused final reduce: last block computes mean(sqrt(min d^2)) ----
    __threadfence();
    if (tid == 0)
        lastf = (atomicAdd(&g_cnt, 1u) == (unsigned)(gridDim.x * gridDim.y - 1));
    __syncthreads();
    if (lastf) {
        float s = 0.f;
        #pragma unroll 8
        for (int j = 0; j < 64; ++j) {           // rowmin2||colmin2 contiguous 16384
            unsigned u = __hip_atomic_load(&rowmin2[tid + 256 * j],
                                           __ATOMIC_RELAXED, __HIP_MEMORY_SCOPE_AGENT);
            s += sqrtf(__uint_as_float(u));
        }
        #pragma unroll
        for (int m = 1; m <= 32; m <<= 1) s += __shfl_xor(s, m, 64);
        if (lane == 0) wsum[w] = s;
        __syncthreads();
        if (tid == 0) out[0] = (wsum[0] + wsum[1] + wsum[2] + wsum[3]) / (float)N_PTS;
    }
}

extern "C" void kernel_launch(void* const* d_in, const int* in_sizes, int n_in,
                              void* d_out, int out_size, void* d_ws, size_t ws_size,
                              hipStream_t stream) {
    const float* set1 = (const float*)d_in[0];
    const float* set2 = (const float*)d_in[1];
    float* out = (float*)d_out;

    // workspace: rowmin2[8192] | colmin2[8192] (contiguous!) | sq1 | sq2 | p1 | p2
    unsigned* rowmin2 = (unsigned*)d_ws;
    unsigned* colmin2 = rowmin2 + N_PTS;
    float* sq1 = (float*)(colmin2 + N_PTS);
    float* sq2 = sq1 + N_PTS;
    ushort* p1 = (ushort*)((char*)d_ws + 128 * 1024);       // 256B-aligned, past headers
    ushort* p2 = p1 + (size_t)N_PTS * D_DIM;

    prep_kernel<<<512, 256, 0, stream>>>(
        set1, set2, p1, p2, sq1, sq2, rowmin2, colmin2);
    tile_kernel<<<dim3(N_PTS / BM, N_PTS / BN), 256, 0, stream>>>(
        p1, p2, sq1, sq2, rowmin2, colmin2, out);
}